// Round 14
// baseline (168.839 us; speedup 1.0000x reference)
//
#include <hip/hip_runtime.h>
#include <math.h>

namespace {

typedef float v2f __attribute__((ext_vector_type(2)));

constexpr int B = 2;
constexpr int F = 4096;      // triangles per batch
constexpr int Q = 16384;     // points per batch
constexpr int NP = B * Q;    // 32768 total points
constexpr int BLOCK = 256;
constexpr int P4 = 4;        // points per lane in screen

// output layout in d_out (float32): dist [NP], closest [NP,3], faces [NP]
constexpr int OFF_DIST = 0;
constexpr int OFF_CP = NP;
constexpr int OFF_FACE = 4 * NP;

// ---------------- exact path (reference-bit-order, contract OFF) -----------

__device__ __forceinline__ float safediv(float num, float den) {
  #pragma clang fp contract(off)
  float d = (fabsf(den) > 1e-12f) ? den : 1.0f;
  return num / d;
}

__device__ __forceinline__ float clamp01(float x) {
  return fminf(fmaxf(x, 0.0f), 1.0f);
}

// Ericson region-based closest point on triangle, mirroring the JAX reference
// op-for-op (including the where/override order). Contract OFF inside.
__device__ __forceinline__ void closest_pt(
    float px, float py, float pz,
    float ax, float ay, float az,
    float bx, float by, float bz,
    float cx, float cy, float cz,
    float& rx, float& ry, float& rz) {
  #pragma clang fp contract(off)
  float abx = bx - ax, aby = by - ay, abz = bz - az;
  float acx = cx - ax, acy = cy - ay, acz = cz - az;
  float apx = px - ax, apy = py - ay, apz = pz - az;
  float d1 = (abx * apx + aby * apy) + abz * apz;
  float d2 = (acx * apx + acy * apy) + acz * apz;
  float bpx = px - bx, bpy = py - by, bpz = pz - bz;
  float d3 = (abx * bpx + aby * bpy) + abz * bpz;
  float d4 = (acx * bpx + acy * bpy) + acz * bpz;
  float cpx = px - cx, cpy = py - cy, cpz = pz - cz;
  float d5 = (abx * cpx + aby * cpy) + abz * cpz;
  float d6 = (acx * cpx + acy * cpy) + acz * cpz;

  float vc = d1 * d4 - d3 * d2;
  float vb = d5 * d2 - d1 * d6;
  float va = d3 * d6 - d5 * d4;

  float v_ab = clamp01(safediv(d1, d1 - d3));
  float w_ac = clamp01(safediv(d2, d2 - d6));
  float w_bc = clamp01(safediv(d4 - d3, (d4 - d3) + (d5 - d6)));

  float denom = (va + vb) + vc;
  float v = safediv(vb, denom);
  float w = safediv(vc, denom);

  float ox = ax + abx * v + acx * w;
  float oy = ay + aby * v + acy * w;
  float oz = az + abz * v + acz * w;

  bool m_bc = (va <= 0.0f) && (d4 - d3 >= 0.0f) && (d5 - d6 >= 0.0f);
  bool m_ac = (vb <= 0.0f) && (d2 >= 0.0f) && (d6 <= 0.0f);
  bool m_ab = (vc <= 0.0f) && (d1 >= 0.0f) && (d3 <= 0.0f);
  bool m_c  = (d6 >= 0.0f) && (d5 <= d6);
  bool m_b  = (d3 >= 0.0f) && (d4 <= d3);
  bool m_a  = (d1 <= 0.0f) && (d2 <= 0.0f);

  if (m_bc) { ox = bx + w_bc * (cx - bx); oy = by + w_bc * (cy - by); oz = bz + w_bc * (cz - bz); }
  if (m_ac) { ox = ax + w_ac * acx;       oy = ay + w_ac * acy;       oz = az + w_ac * acz; }
  if (m_ab) { ox = ax + v_ab * abx;       oy = ay + v_ab * aby;       oz = az + v_ab * abz; }
  if (m_c)  { ox = cx; oy = cy; oz = cz; }
  if (m_b)  { ox = bx; oy = by; oz = bz; }
  if (m_a)  { ox = ax; oy = ay; oz = az; }

  rx = ox; ry = oy; rz = oz;
}

__device__ __forceinline__ float exact_d2(
    float px, float py, float pz, const float* __restrict__ g /*a,b,c*/) {
  #pragma clang fp contract(off)
  float rx, ry, rz;
  closest_pt(px, py, pz,
             g[0], g[1], g[2], g[3], g[4], g[5], g[6], g[7], g[8],
             rx, ry, rz);
  float dx = px - rx, dy = py - ry, dz = pz - rz;
  return (dx * dx + dy * dy) + dz * dz;
}

// ---------------- key helpers ----------------------------------------------

__device__ __forceinline__ unsigned umin2(unsigned a, unsigned b) { return a < b ? a : b; }
__device__ __forceinline__ unsigned umax2(unsigned a, unsigned b) { return a > b ? a : b; }

// sorted top-2 insert via min/max (3 VOP2 ops)
__device__ __forceinline__ void ins2(unsigned k, unsigned& K1, unsigned& K2) {
  unsigned t = umax2(K1, k);
  K1 = umin2(K1, k);
  K2 = umin2(K2, t);
}

// sorted top-8 insert via min/max network
__device__ __forceinline__ void ins8(unsigned k,
    unsigned& K1, unsigned& K2, unsigned& K3, unsigned& K4,
    unsigned& K5, unsigned& K6, unsigned& K7, unsigned& K8) {
  unsigned t;
  t = umax2(K1, k); K1 = umin2(K1, k);
  k = t; t = umax2(K2, k); K2 = umin2(K2, k);
  k = t; t = umax2(K3, k); K3 = umin2(K3, k);
  k = t; t = umax2(K4, k); K4 = umin2(K4, k);
  k = t; t = umax2(K5, k); K5 = umin2(K5, k);
  k = t; t = umax2(K6, k); K6 = umin2(K6, k);
  k = t; t = umax2(K7, k); K7 = umin2(K7, k);
  K8 = umin2(K8, t);
}

// scalar finish of one point's screen value: returns packed key
__device__ __forceinline__ unsigned fin_one(
    float dint, float tabm, float tacm, float tbcm,
    float td1, float td2, float ap2m, float bp2, float t43d,
    float va, float vb, float vc,
    float aa, float bb, float cc, float pp, int gidx) {
  float tab = __builtin_amdgcn_fmed3f(tabm, 0.0f, 1.0f);
  float sab = fmaf(-tab, fmaf(-tab, aa, td1), ap2m);
  float tac = __builtin_amdgcn_fmed3f(tacm, 0.0f, 1.0f);
  float sac = fmaf(-tac, fmaf(-tac, bb, td2), ap2m);
  float tbc = __builtin_amdgcn_fmed3f(tbcm, 0.0f, 1.0f);
  float sbc = fmaf(-tbc, fmaf(-tbc, cc, t43d), bp2);
  float dseg = fminf(fminf(sab, sac), sbc);        // v_min3
  float mv   = fminf(fminf(va, vb), vc);           // v_min3
  float d = (mv > 0.0f) ? dint : dseg;
  d = fmaxf(d + pp, 0.0f);                         // restore |p|^2, keep >=0
  return (__float_as_uint(d) & 0xFFFFF000u) | (unsigned)gidx;
}

// v2f extraction from a float4 quad (sub-register aliasing, no moves)
struct q2 { v2f lo, hi; };
__device__ __forceinline__ q2 as2(float4 q) {
  q2 r; r.lo = v2f{q.x, q.y}; r.hi = v2f{q.z, q.w}; return r;
}

// ---------------- screen: LDS pre-SPLATTED v2f records, P=4 ----------------
// Per triangle: 10 float4 granules, each {c,c,d,d} (constants stored twice so
// the inner loop reads genuine v2f operands -> v_pk_*_f32 with no splat cost):
//  q0={abx,abx,aby,aby} q1={abz,abz,c1,c1}   q2={acx,acx,acy,acy}
//  q3={acz,acz,c2,c2}   q4={-2ax,-2ax,-2ay,-2ay} q5={-2az,-2az,|a|^2,|a|^2}
//  q6={aa,aa,bb,bb}     q7={abac,abac,cc,cc} q8={raa,raa,rbb,rbb}
//  q9={rcc,rcc,rdn,rdn}
// c1=-(a.ab), c2=-(a.ac). Screen works on d^2-|p|^2; |p|^2 restored in fin.

template <int NC, int WPE>
__global__ __launch_bounds__(BLOCK, WPE) void bvh_screen4(
    const float* __restrict__ tris,   // [B, F, 3, 3]
    const float* __restrict__ pts,    // [B, Q, 3]
    uint2* __restrict__ keys) {       // [NC, NP]
  constexpr int CFL = F / NC;
  __shared__ float4 s_rec[10 * CFL];  // AoS: s_rec[t*10 + k]

  constexpr int BPB = (Q / P4) / BLOCK;          // 16
  const int batch = blockIdx.x / BPB;            // uniform per block
  const int j = (blockIdx.x % BPB) * BLOCK + threadIdx.x;  // 0 .. Q/4-1
  const int chunk = blockIdx.y;
  const int tri0 = chunk * CFL;
  const float* tb = tris + (size_t)batch * F * 9;

  for (int t = threadIdx.x; t < CFL; t += BLOCK) {
    const float* g = tb + (size_t)(tri0 + t) * 9;
    float ax = g[0], ay = g[1], az = g[2];
    float abx = g[3] - ax, aby = g[4] - ay, abz = g[5] - az;
    float acx = g[6] - ax, acy = g[7] - ay, acz = g[8] - az;
    float aa   = abx * abx + aby * aby + abz * abz;
    float bb   = acx * acx + acy * acy + acz * acz;
    float abac = abx * acx + aby * acy + abz * acz;
    float bcx = acx - abx, bcy = acy - aby, bcz = acz - abz;
    float cc   = bcx * bcx + bcy * bcy + bcz * bcz;
    float nx = aby * acz - abz * acy;
    float ny = abz * acx - abx * acz;
    float nz = abx * acy - aby * acx;
    float n2 = nx * nx + ny * ny + nz * nz;
    float raa = (aa > 1e-12f) ? 1.0f / aa : 1.0f;     // safediv-style guards
    float rbb = (bb > 1e-12f) ? 1.0f / bb : 1.0f;
    float rcc = (cc > 1e-12f) ? 1.0f / cc : 1.0f;
    float rdn = (n2 > 1e-12f) ? 1.0f / n2 : 1.0f;
    float c1 = -(ax * abx + ay * aby + az * abz);
    float c2 = -(ax * acx + ay * acy + az * acz);
    float caa2 = ax * ax + ay * ay + az * az;
    float4* s = &s_rec[t * 10];
    s[0] = make_float4(abx, abx, aby, aby);
    s[1] = make_float4(abz, abz, c1, c1);
    s[2] = make_float4(acx, acx, acy, acy);
    s[3] = make_float4(acz, acz, c2, c2);
    s[4] = make_float4(-2.0f * ax, -2.0f * ax, -2.0f * ay, -2.0f * ay);
    s[5] = make_float4(-2.0f * az, -2.0f * az, caa2, caa2);
    s[6] = make_float4(aa, aa, bb, bb);
    s[7] = make_float4(abac, abac, cc, cc);
    s[8] = make_float4(raa, raa, rbb, rbb);
    s[9] = make_float4(rcc, rcc, rdn, rdn);
  }
  __syncthreads();

  const int p0 = batch * Q + j;
  float px0 = pts[(p0          ) * 3 + 0], py0 = pts[(p0          ) * 3 + 1], pz0 = pts[(p0          ) * 3 + 2];
  float px1 = pts[(p0 + Q/4    ) * 3 + 0], py1 = pts[(p0 + Q/4    ) * 3 + 1], pz1 = pts[(p0 + Q/4    ) * 3 + 2];
  float px2 = pts[(p0 + Q/2    ) * 3 + 0], py2 = pts[(p0 + Q/2    ) * 3 + 1], pz2 = pts[(p0 + Q/2    ) * 3 + 2];
  float px3 = pts[(p0 + 3*(Q/4)) * 3 + 0], py3 = pts[(p0 + 3*(Q/4)) * 3 + 1], pz3 = pts[(p0 + 3*(Q/4)) * 3 + 2];

  const v2f pxA = {px0, px1}, pyA = {py0, py1}, pzA = {pz0, pz1};
  const v2f pxB = {px2, px3}, pyB = {py2, py3}, pzB = {pz2, pz3};
  const float pp0 = px0*px0 + py0*py0 + pz0*pz0;
  const float pp1 = px1*px1 + py1*py1 + pz1*pz1;
  const float pp2 = px2*px2 + py2*py2 + pz2*pz2;
  const float pp3 = px3*px3 + py3*py3 + pz3*pz3;

  unsigned A1 = ~0u, A2 = ~0u, Bk1 = ~0u, Bk2 = ~0u;
  unsigned C1 = ~0u, C2 = ~0u, D1 = ~0u, D2 = ~0u;

  {
    #pragma clang fp contract(fast)
    for (int t = 0; t < CFL; ++t) {
      const float4* rp = &s_rec[t * 10];   // uniform addr -> broadcast
      q2 g0 = as2(rp[0]);  // ABX, ABY
      q2 g1 = as2(rp[1]);  // ABZ, C1
      q2 g2 = as2(rp[2]);  // ACX, ACY
      q2 g3 = as2(rp[3]);  // ACZ, C2
      q2 g4 = as2(rp[4]);  // M2AX, M2AY
      q2 g5 = as2(rp[5]);  // M2AZ, CAA2
      q2 g6 = as2(rp[6]);  // AA, BB
      q2 g7 = as2(rp[7]);  // ABAC, CC
      q2 g8 = as2(rp[8]);  // RAA, RBB
      q2 g9 = as2(rp[9]);  // RCC, RDN
      const int gidx = tri0 + t;
      const float aa_s = g6.lo.x, bb_s = g6.hi.x, cc_s = g7.hi.x;

      // ---- pair A (points 0,1): all-v2f math ----
      {
        v2f d1   = pxA * g0.lo + pyA * g0.hi + pzA * g1.lo + g1.hi;
        v2f d2   = pxA * g2.lo + pyA * g2.hi + pzA * g3.lo + g3.hi;
        v2f ap2m = pxA * g4.lo + pyA * g4.hi + pzA * g5.lo + g5.hi;
        v2f d3 = d1 - g6.lo, d6 = d2 - g6.hi, d4 = d2 - g7.lo, d5 = d1 - g7.lo;
        v2f t43 = d4 - d3;
        v2f va = d3 * d6 - d5 * d4;
        v2f vb = d5 * d2 - d1 * d6;
        v2f vc = d1 * d4 - d3 * d2;
        v2f td1 = d1 + d1, td2 = d2 + d2;
        v2f v = vb * g9.hi, w = vc * g9.hi;
        v2f h1 = v * g6.lo + (w * g7.lo - td1);
        v2f h2 = w * g6.hi + (v * g7.lo - td2);
        v2f dint = ap2m + (v * h1 + w * h2);
        v2f tabm = d1 * g8.lo, tacm = d2 * g8.hi, tbcm = t43 * g9.lo;
        v2f bp2 = (ap2m - td1) + g6.lo;
        v2f t43d = t43 + t43;
        ins2(fin_one(dint.x, tabm.x, tacm.x, tbcm.x, td1.x, td2.x, ap2m.x,
                     bp2.x, t43d.x, va.x, vb.x, vc.x,
                     aa_s, bb_s, cc_s, pp0, gidx), A1, A2);
        ins2(fin_one(dint.y, tabm.y, tacm.y, tbcm.y, td1.y, td2.y, ap2m.y,
                     bp2.y, t43d.y, va.y, vb.y, vc.y,
                     aa_s, bb_s, cc_s, pp1, gidx), Bk1, Bk2);
      }
      // ---- pair B (points 2,3) ----
      {
        v2f d1   = pxB * g0.lo + pyB * g0.hi + pzB * g1.lo + g1.hi;
        v2f d2   = pxB * g2.lo + pyB * g2.hi + pzB * g3.lo + g3.hi;
        v2f ap2m = pxB * g4.lo + pyB * g4.hi + pzB * g5.lo + g5.hi;
        v2f d3 = d1 - g6.lo, d6 = d2 - g6.hi, d4 = d2 - g7.lo, d5 = d1 - g7.lo;
        v2f t43 = d4 - d3;
        v2f va = d3 * d6 - d5 * d4;
        v2f vb = d5 * d2 - d1 * d6;
        v2f vc = d1 * d4 - d3 * d2;
        v2f td1 = d1 + d1, td2 = d2 + d2;
        v2f v = vb * g9.hi, w = vc * g9.hi;
        v2f h1 = v * g6.lo + (w * g7.lo - td1);
        v2f h2 = w * g6.hi + (v * g7.lo - td2);
        v2f dint = ap2m + (v * h1 + w * h2);
        v2f tabm = d1 * g8.lo, tacm = d2 * g8.hi, tbcm = t43 * g9.lo;
        v2f bp2 = (ap2m - td1) + g6.lo;
        v2f t43d = t43 + t43;
        ins2(fin_one(dint.x, tabm.x, tacm.x, tbcm.x, td1.x, td2.x, ap2m.x,
                     bp2.x, t43d.x, va.x, vb.x, vc.x,
                     aa_s, bb_s, cc_s, pp2, gidx), C1, C2);
        ins2(fin_one(dint.y, tabm.y, tacm.y, tbcm.y, td1.y, td2.y, ap2m.y,
                     bp2.y, t43d.y, va.y, vb.y, vc.y,
                     aa_s, bb_s, cc_s, pp3, gidx), D1, D2);
      }
    }
  }

  keys[(size_t)chunk * NP + p0            ] = make_uint2(A1, A2);
  keys[(size_t)chunk * NP + p0 + Q/4      ] = make_uint2(Bk1, Bk2);
  keys[(size_t)chunk * NP + p0 + Q/2      ] = make_uint2(C1, C2);
  keys[(size_t)chunk * NP + p0 + 3*(Q/4)  ] = make_uint2(D1, D2);
}

// ---------------- finish: merge 2*NC keys -> top-8 -> exact ----------------

template <int NC>
__global__ __launch_bounds__(BLOCK) void bvh_finish2(
    const float* __restrict__ tris,
    const float* __restrict__ pts,
    const uint2* __restrict__ keys,
    float* __restrict__ out) {
  const int gpt = blockIdx.x * BLOCK + threadIdx.x;
  if (gpt >= NP) return;

  unsigned K1 = ~0u, K2 = ~0u, K3 = ~0u, K4 = ~0u;
  unsigned K5 = ~0u, K6 = ~0u, K7 = ~0u, K8 = ~0u;
  for (int c = 0; c < NC; ++c) {
    uint2 k = keys[(size_t)c * NP + gpt];
    ins8(k.x, K1, K2, K3, K4, K5, K6, K7, K8);
    ins8(k.y, K1, K2, K3, K4, K5, K6, K7, K8);
  }

  const int batch = gpt / Q;
  const float* tb = tris + (size_t)batch * F * 9;
  const float px = pts[gpt * 3 + 0];
  const float py = pts[gpt * 3 + 1];
  const float pz = pts[gpt * 3 + 2];

  // order-independent first-occurrence argmin over the 8 candidates
  float be = INFINITY;
  int bi = 0x7FFFFFFF;
  #define CAND(Kx) { int t_ = (int)(Kx & 0xFFFu); \
    float d_ = exact_d2(px, py, pz, tb + (size_t)t_ * 9); \
    if (d_ < be || (d_ == be && t_ < bi)) { be = d_; bi = t_; } }
  CAND(K1) CAND(K2) CAND(K3) CAND(K4) CAND(K5) CAND(K6) CAND(K7) CAND(K8)
  #undef CAND

  const float* tr = tb + (size_t)bi * 9;
  float rx, ry, rz;
  closest_pt(px, py, pz,
             tr[0], tr[1], tr[2], tr[3], tr[4], tr[5], tr[6], tr[7], tr[8],
             rx, ry, rz);

  out[OFF_DIST + gpt] = be;
  out[OFF_CP + gpt * 3 + 0] = rx;
  out[OFF_CP + gpt * 3 + 1] = ry;
  out[OFF_CP + gpt * 3 + 2] = rz;
  out[OFF_FACE + gpt] = (float)bi;
}

}  // namespace

extern "C" void kernel_launch(void* const* d_in, const int* in_sizes, int n_in,
                              void* d_out, int out_size, void* d_ws, size_t ws_size,
                              hipStream_t stream) {
  const float* tris = (const float*)d_in[0];
  const float* pts  = (const float*)d_in[1];
  float* out = (float*)d_out;

  dim3 grid2((NP + BLOCK - 1) / BLOCK);
  const int gx = B * ((Q / P4) / BLOCK);   // 32 blocks in x

  constexpr size_t KEY64_BYTES = (size_t)64 * NP * sizeof(uint2);  // 16 MiB

  if (ws_size >= KEY64_BYTES) {
    // NC=64, WPE=5: VGPR budget ~102 (splatted-record loop needs ~90), 5 waves/SIMD
    uint2* keys = (uint2*)d_ws;
    bvh_screen4<64, 5><<<dim3(gx, 64), BLOCK, 0, stream>>>(tris, pts, keys);
    bvh_finish2<64><<<grid2, BLOCK, 0, stream>>>(tris, pts, keys, out);
  } else {
    // 8 MiB tier: NC=32, WPE=4
    uint2* keys = (uint2*)d_ws;
    bvh_screen4<32, 4><<<dim3(gx, 32), BLOCK, 0, stream>>>(tris, pts, keys);
    bvh_finish2<32><<<grid2, BLOCK, 0, stream>>>(tris, pts, keys, out);
  }
}

// Round 15
// 166.870 us; speedup vs baseline: 1.0118x; 1.0118x over previous
//
#include <hip/hip_runtime.h>
#include <math.h>

namespace {

typedef float v2f __attribute__((ext_vector_type(2)));

constexpr int B = 2;
constexpr int F = 4096;      // triangles per batch
constexpr int Q = 16384;     // points per batch
constexpr int NP = B * Q;    // 32768 total points
constexpr int BLOCK = 256;
constexpr int P4 = 4;        // points per lane in screen

// output layout in d_out (float32): dist [NP], closest [NP,3], faces [NP]
constexpr int OFF_DIST = 0;
constexpr int OFF_CP = NP;
constexpr int OFF_FACE = 4 * NP;

// ---------------- exact path (reference-bit-order, contract OFF) -----------

__device__ __forceinline__ float safediv(float num, float den) {
  #pragma clang fp contract(off)
  float d = (fabsf(den) > 1e-12f) ? den : 1.0f;
  return num / d;
}

__device__ __forceinline__ float clamp01(float x) {
  return fminf(fmaxf(x, 0.0f), 1.0f);
}

// Ericson region-based closest point on triangle, mirroring the JAX reference
// op-for-op (including the where/override order). Contract OFF inside.
__device__ __forceinline__ void closest_pt(
    float px, float py, float pz,
    float ax, float ay, float az,
    float bx, float by, float bz,
    float cx, float cy, float cz,
    float& rx, float& ry, float& rz) {
  #pragma clang fp contract(off)
  float abx = bx - ax, aby = by - ay, abz = bz - az;
  float acx = cx - ax, acy = cy - ay, acz = cz - az;
  float apx = px - ax, apy = py - ay, apz = pz - az;
  float d1 = (abx * apx + aby * apy) + abz * apz;
  float d2 = (acx * apx + acy * apy) + acz * apz;
  float bpx = px - bx, bpy = py - by, bpz = pz - bz;
  float d3 = (abx * bpx + aby * bpy) + abz * bpz;
  float d4 = (acx * bpx + acy * bpy) + acz * bpz;
  float cpx = px - cx, cpy = py - cy, cpz = pz - cz;
  float d5 = (abx * cpx + aby * cpy) + abz * cpz;
  float d6 = (acx * cpx + acy * cpy) + acz * cpz;

  float vc = d1 * d4 - d3 * d2;
  float vb = d5 * d2 - d1 * d6;
  float va = d3 * d6 - d5 * d4;

  float v_ab = clamp01(safediv(d1, d1 - d3));
  float w_ac = clamp01(safediv(d2, d2 - d6));
  float w_bc = clamp01(safediv(d4 - d3, (d4 - d3) + (d5 - d6)));

  float denom = (va + vb) + vc;
  float v = safediv(vb, denom);
  float w = safediv(vc, denom);

  float ox = ax + abx * v + acx * w;
  float oy = ay + aby * v + acy * w;
  float oz = az + abz * v + acz * w;

  bool m_bc = (va <= 0.0f) && (d4 - d3 >= 0.0f) && (d5 - d6 >= 0.0f);
  bool m_ac = (vb <= 0.0f) && (d2 >= 0.0f) && (d6 <= 0.0f);
  bool m_ab = (vc <= 0.0f) && (d1 >= 0.0f) && (d3 <= 0.0f);
  bool m_c  = (d6 >= 0.0f) && (d5 <= d6);
  bool m_b  = (d3 >= 0.0f) && (d4 <= d3);
  bool m_a  = (d1 <= 0.0f) && (d2 <= 0.0f);

  if (m_bc) { ox = bx + w_bc * (cx - bx); oy = by + w_bc * (cy - by); oz = bz + w_bc * (cz - bz); }
  if (m_ac) { ox = ax + w_ac * acx;       oy = ay + w_ac * acy;       oz = az + w_ac * acz; }
  if (m_ab) { ox = ax + v_ab * abx;       oy = ay + v_ab * aby;       oz = az + v_ab * abz; }
  if (m_c)  { ox = cx; oy = cy; oz = cz; }
  if (m_b)  { ox = bx; oy = by; oz = bz; }
  if (m_a)  { ox = ax; oy = ay; oz = az; }

  rx = ox; ry = oy; rz = oz;
}

__device__ __forceinline__ float exact_d2(
    float px, float py, float pz, const float* __restrict__ g /*a,b,c*/) {
  #pragma clang fp contract(off)
  float rx, ry, rz;
  closest_pt(px, py, pz,
             g[0], g[1], g[2], g[3], g[4], g[5], g[6], g[7], g[8],
             rx, ry, rz);
  float dx = px - rx, dy = py - ry, dz = pz - rz;
  return (dx * dx + dy * dy) + dz * dz;
}

// ---------------- key helpers ----------------------------------------------

__device__ __forceinline__ unsigned umin2(unsigned a, unsigned b) { return a < b ? a : b; }
__device__ __forceinline__ unsigned umax2(unsigned a, unsigned b) { return a > b ? a : b; }

// sorted top-2 insert via min/max (3 VOP2 ops)
__device__ __forceinline__ void ins2(unsigned k, unsigned& K1, unsigned& K2) {
  unsigned t = umax2(K1, k);
  K1 = umin2(K1, k);
  K2 = umin2(K2, t);
}

// sorted top-8 insert via min/max network
__device__ __forceinline__ void ins8(unsigned k,
    unsigned& K1, unsigned& K2, unsigned& K3, unsigned& K4,
    unsigned& K5, unsigned& K6, unsigned& K7, unsigned& K8) {
  unsigned t;
  t = umax2(K1, k); K1 = umin2(K1, k);
  k = t; t = umax2(K2, k); K2 = umin2(K2, k);
  k = t; t = umax2(K3, k); K3 = umin2(K3, k);
  k = t; t = umax2(K4, k); K4 = umin2(K4, k);
  k = t; t = umax2(K5, k); K5 = umin2(K5, k);
  k = t; t = umax2(K6, k); K6 = umin2(K6, k);
  k = t; t = umax2(K7, k); K7 = umin2(K7, k);
  K8 = umin2(K8, t);
}

// scalar finish of one point's screen value: returns packed key
__device__ __forceinline__ unsigned fin_one(
    float dint, float tabm, float tacm, float tbcm,
    float td1, float td2, float ap2m, float bp2, float t43d,
    float va, float vb, float vc,
    float aa, float bb, float cc, float pp, int gidx) {
  float tab = __builtin_amdgcn_fmed3f(tabm, 0.0f, 1.0f);
  float sab = fmaf(-tab, fmaf(-tab, aa, td1), ap2m);
  float tac = __builtin_amdgcn_fmed3f(tacm, 0.0f, 1.0f);
  float sac = fmaf(-tac, fmaf(-tac, bb, td2), ap2m);
  float tbc = __builtin_amdgcn_fmed3f(tbcm, 0.0f, 1.0f);
  float sbc = fmaf(-tbc, fmaf(-tbc, cc, t43d), bp2);
  float dseg = fminf(fminf(sab, sac), sbc);        // v_min3
  float mv   = fminf(fminf(va, vb), vc);           // v_min3
  float d = (mv > 0.0f) ? dint : dseg;
  d = fmaxf(d + pp, 0.0f);                         // restore |p|^2, keep >=0
  return (__float_as_uint(d) & 0xFFFFF000u) | (unsigned)gidx;
}

// ---------------- screen: LDS splatted v2f records, direct v2f loads -------
// Per triangle: 40 floats = 20 x {c,c} granules, loaded as v2f (ds_read_b64
// into aligned VGPR pairs -> native v_pk_*_f32 operands, no repacking):
//  [abx abx][aby aby][abz abz][c1 c1][acx acx][acy acy][acz acz][c2 c2]
//  [-2ax -2ax][-2ay -2ay][-2az -2az][|a|2 |a|2][aa aa][bb bb][abac abac]
//  [cc cc][raa raa][rbb rbb][rcc rcc][rdn rdn]
// c1=-(a.ab), c2=-(a.ac). Screen works on d^2-|p|^2; |p|^2 restored in fin.

template <int NC, int WPE>
__global__ __launch_bounds__(BLOCK, WPE) void bvh_screen4(
    const float* __restrict__ tris,   // [B, F, 3, 3]
    const float* __restrict__ pts,    // [B, Q, 3]
    uint2* __restrict__ keys) {       // [NC, NP]
  constexpr int CFL = F / NC;
  __shared__ float4 s_rec[10 * CFL];  // AoS: 10 quads = 20 v2f granules / tri

  constexpr int BPB = (Q / P4) / BLOCK;          // 16
  const int batch = blockIdx.x / BPB;            // uniform per block
  const int j = (blockIdx.x % BPB) * BLOCK + threadIdx.x;  // 0 .. Q/4-1
  const int chunk = blockIdx.y;
  const int tri0 = chunk * CFL;
  const float* tb = tris + (size_t)batch * F * 9;

  for (int t = threadIdx.x; t < CFL; t += BLOCK) {
    const float* g = tb + (size_t)(tri0 + t) * 9;
    float ax = g[0], ay = g[1], az = g[2];
    float abx = g[3] - ax, aby = g[4] - ay, abz = g[5] - az;
    float acx = g[6] - ax, acy = g[7] - ay, acz = g[8] - az;
    float aa   = abx * abx + aby * aby + abz * abz;
    float bb   = acx * acx + acy * acy + acz * acz;
    float abac = abx * acx + aby * acy + abz * acz;
    float bcx = acx - abx, bcy = acy - aby, bcz = acz - abz;
    float cc   = bcx * bcx + bcy * bcy + bcz * bcz;
    float nx = aby * acz - abz * acy;
    float ny = abz * acx - abx * acz;
    float nz = abx * acy - aby * acx;
    float n2 = nx * nx + ny * ny + nz * nz;
    float raa = (aa > 1e-12f) ? 1.0f / aa : 1.0f;     // safediv-style guards
    float rbb = (bb > 1e-12f) ? 1.0f / bb : 1.0f;
    float rcc = (cc > 1e-12f) ? 1.0f / cc : 1.0f;
    float rdn = (n2 > 1e-12f) ? 1.0f / n2 : 1.0f;
    float c1 = -(ax * abx + ay * aby + az * abz);
    float c2 = -(ax * acx + ay * acy + az * acz);
    float caa2 = ax * ax + ay * ay + az * az;
    float4* s = &s_rec[t * 10];
    s[0] = make_float4(abx, abx, aby, aby);
    s[1] = make_float4(abz, abz, c1, c1);
    s[2] = make_float4(acx, acx, acy, acy);
    s[3] = make_float4(acz, acz, c2, c2);
    s[4] = make_float4(-2.0f * ax, -2.0f * ax, -2.0f * ay, -2.0f * ay);
    s[5] = make_float4(-2.0f * az, -2.0f * az, caa2, caa2);
    s[6] = make_float4(aa, aa, bb, bb);
    s[7] = make_float4(abac, abac, cc, cc);
    s[8] = make_float4(raa, raa, rbb, rbb);
    s[9] = make_float4(rcc, rcc, rdn, rdn);
  }
  __syncthreads();

  const int p0 = batch * Q + j;
  float px0 = pts[(p0          ) * 3 + 0], py0 = pts[(p0          ) * 3 + 1], pz0 = pts[(p0          ) * 3 + 2];
  float px1 = pts[(p0 + Q/4    ) * 3 + 0], py1 = pts[(p0 + Q/4    ) * 3 + 1], pz1 = pts[(p0 + Q/4    ) * 3 + 2];
  float px2 = pts[(p0 + Q/2    ) * 3 + 0], py2 = pts[(p0 + Q/2    ) * 3 + 1], pz2 = pts[(p0 + Q/2    ) * 3 + 2];
  float px3 = pts[(p0 + 3*(Q/4)) * 3 + 0], py3 = pts[(p0 + 3*(Q/4)) * 3 + 1], pz3 = pts[(p0 + 3*(Q/4)) * 3 + 2];

  const v2f pxA = {px0, px1}, pyA = {py0, py1}, pzA = {pz0, pz1};
  const v2f pxB = {px2, px3}, pyB = {py2, py3}, pzB = {pz2, pz3};
  const float pp0 = px0*px0 + py0*py0 + pz0*pz0;
  const float pp1 = px1*px1 + py1*py1 + pz1*pz1;
  const float pp2 = px2*px2 + py2*py2 + pz2*pz2;
  const float pp3 = px3*px3 + py3*py3 + pz3*pz3;

  unsigned A1 = ~0u, A2 = ~0u, Bk1 = ~0u, Bk2 = ~0u;
  unsigned C1 = ~0u, C2 = ~0u, D1 = ~0u, D2 = ~0u;

  {
    #pragma clang fp contract(fast)
    for (int t = 0; t < CFL; ++t) {
      const float* sp = (const float*)&s_rec[t * 10];  // uniform addr
      // direct v2f loads (ds_read_b64 -> aligned VGPR pairs)
      v2f ABX  = *(const v2f*)(sp + 0);
      v2f ABY  = *(const v2f*)(sp + 2);
      v2f ABZ  = *(const v2f*)(sp + 4);
      v2f C1c  = *(const v2f*)(sp + 6);
      v2f ACX  = *(const v2f*)(sp + 8);
      v2f ACY  = *(const v2f*)(sp + 10);
      v2f ACZ  = *(const v2f*)(sp + 12);
      v2f C2c  = *(const v2f*)(sp + 14);
      v2f M2AX = *(const v2f*)(sp + 16);
      v2f M2AY = *(const v2f*)(sp + 18);
      v2f M2AZ = *(const v2f*)(sp + 20);
      v2f CAA2 = *(const v2f*)(sp + 22);
      v2f AA   = *(const v2f*)(sp + 24);
      v2f BBv  = *(const v2f*)(sp + 26);
      v2f ABAC = *(const v2f*)(sp + 28);
      v2f CCv  = *(const v2f*)(sp + 30);
      v2f RAA  = *(const v2f*)(sp + 32);
      v2f RBB  = *(const v2f*)(sp + 34);
      v2f RCC  = *(const v2f*)(sp + 36);
      v2f RDN  = *(const v2f*)(sp + 38);
      const int gidx = tri0 + t;
      const float aa_s = AA.x, bb_s = BBv.x, cc_s = CCv.x;

      // ---- pair A (points 0,1): all-v2f math ----
      {
        v2f d1   = pxA * ABX + pyA * ABY + pzA * ABZ + C1c;
        v2f d2   = pxA * ACX + pyA * ACY + pzA * ACZ + C2c;
        v2f ap2m = pxA * M2AX + pyA * M2AY + pzA * M2AZ + CAA2;
        v2f d3 = d1 - AA, d6 = d2 - BBv, d4 = d2 - ABAC, d5 = d1 - ABAC;
        v2f t43 = d4 - d3;
        v2f va = d3 * d6 - d5 * d4;
        v2f vb = d5 * d2 - d1 * d6;
        v2f vc = d1 * d4 - d3 * d2;
        v2f td1 = d1 + d1, td2 = d2 + d2;
        v2f v = vb * RDN, w = vc * RDN;
        v2f h1 = v * AA + (w * ABAC - td1);
        v2f h2 = w * BBv + (v * ABAC - td2);
        v2f dint = ap2m + (v * h1 + w * h2);
        v2f tabm = d1 * RAA, tacm = d2 * RBB, tbcm = t43 * RCC;
        v2f bp2 = (ap2m - td1) + AA;
        v2f t43d = t43 + t43;
        ins2(fin_one(dint.x, tabm.x, tacm.x, tbcm.x, td1.x, td2.x, ap2m.x,
                     bp2.x, t43d.x, va.x, vb.x, vc.x,
                     aa_s, bb_s, cc_s, pp0, gidx), A1, A2);
        ins2(fin_one(dint.y, tabm.y, tacm.y, tbcm.y, td1.y, td2.y, ap2m.y,
                     bp2.y, t43d.y, va.y, vb.y, vc.y,
                     aa_s, bb_s, cc_s, pp1, gidx), Bk1, Bk2);
      }
      // ---- pair B (points 2,3) ----
      {
        v2f d1   = pxB * ABX + pyB * ABY + pzB * ABZ + C1c;
        v2f d2   = pxB * ACX + pyB * ACY + pzB * ACZ + C2c;
        v2f ap2m = pxB * M2AX + pyB * M2AY + pzB * M2AZ + CAA2;
        v2f d3 = d1 - AA, d6 = d2 - BBv, d4 = d2 - ABAC, d5 = d1 - ABAC;
        v2f t43 = d4 - d3;
        v2f va = d3 * d6 - d5 * d4;
        v2f vb = d5 * d2 - d1 * d6;
        v2f vc = d1 * d4 - d3 * d2;
        v2f td1 = d1 + d1, td2 = d2 + d2;
        v2f v = vb * RDN, w = vc * RDN;
        v2f h1 = v * AA + (w * ABAC - td1);
        v2f h2 = w * BBv + (v * ABAC - td2);
        v2f dint = ap2m + (v * h1 + w * h2);
        v2f tabm = d1 * RAA, tacm = d2 * RBB, tbcm = t43 * RCC;
        v2f bp2 = (ap2m - td1) + AA;
        v2f t43d = t43 + t43;
        ins2(fin_one(dint.x, tabm.x, tacm.x, tbcm.x, td1.x, td2.x, ap2m.x,
                     bp2.x, t43d.x, va.x, vb.x, vc.x,
                     aa_s, bb_s, cc_s, pp2, gidx), C1, C2);
        ins2(fin_one(dint.y, tabm.y, tacm.y, tbcm.y, td1.y, td2.y, ap2m.y,
                     bp2.y, t43d.y, va.y, vb.y, vc.y,
                     aa_s, bb_s, cc_s, pp3, gidx), D1, D2);
      }
    }
  }

  keys[(size_t)chunk * NP + p0            ] = make_uint2(A1, A2);
  keys[(size_t)chunk * NP + p0 + Q/4      ] = make_uint2(Bk1, Bk2);
  keys[(size_t)chunk * NP + p0 + Q/2      ] = make_uint2(C1, C2);
  keys[(size_t)chunk * NP + p0 + 3*(Q/4)  ] = make_uint2(D1, D2);
}

// ---------------- finish: merge 2*NC keys -> top-8 -> exact ----------------

template <int NC>
__global__ __launch_bounds__(BLOCK) void bvh_finish2(
    const float* __restrict__ tris,
    const float* __restrict__ pts,
    const uint2* __restrict__ keys,
    float* __restrict__ out) {
  const int gpt = blockIdx.x * BLOCK + threadIdx.x;
  if (gpt >= NP) return;

  unsigned K1 = ~0u, K2 = ~0u, K3 = ~0u, K4 = ~0u;
  unsigned K5 = ~0u, K6 = ~0u, K7 = ~0u, K8 = ~0u;
  for (int c = 0; c < NC; ++c) {
    uint2 k = keys[(size_t)c * NP + gpt];
    ins8(k.x, K1, K2, K3, K4, K5, K6, K7, K8);
    ins8(k.y, K1, K2, K3, K4, K5, K6, K7, K8);
  }

  const int batch = gpt / Q;
  const float* tb = tris + (size_t)batch * F * 9;
  const float px = pts[gpt * 3 + 0];
  const float py = pts[gpt * 3 + 1];
  const float pz = pts[gpt * 3 + 2];

  // order-independent first-occurrence argmin over the 8 candidates
  float be = INFINITY;
  int bi = 0x7FFFFFFF;
  #define CAND(Kx) { int t_ = (int)(Kx & 0xFFFu); \
    float d_ = exact_d2(px, py, pz, tb + (size_t)t_ * 9); \
    if (d_ < be || (d_ == be && t_ < bi)) { be = d_; bi = t_; } }
  CAND(K1) CAND(K2) CAND(K3) CAND(K4) CAND(K5) CAND(K6) CAND(K7) CAND(K8)
  #undef CAND

  const float* tr = tb + (size_t)bi * 9;
  float rx, ry, rz;
  closest_pt(px, py, pz,
             tr[0], tr[1], tr[2], tr[3], tr[4], tr[5], tr[6], tr[7], tr[8],
             rx, ry, rz);

  out[OFF_DIST + gpt] = be;
  out[OFF_CP + gpt * 3 + 0] = rx;
  out[OFF_CP + gpt * 3 + 1] = ry;
  out[OFF_CP + gpt * 3 + 2] = rz;
  out[OFF_FACE + gpt] = (float)bi;
}

}  // namespace

extern "C" void kernel_launch(void* const* d_in, const int* in_sizes, int n_in,
                              void* d_out, int out_size, void* d_ws, size_t ws_size,
                              hipStream_t stream) {
  const float* tris = (const float*)d_in[0];
  const float* pts  = (const float*)d_in[1];
  float* out = (float*)d_out;

  dim3 grid2((NP + BLOCK - 1) / BLOCK);
  const int gx = B * ((Q / P4) / BLOCK);   // 32 blocks in x

  constexpr size_t KEY64_BYTES = (size_t)64 * NP * sizeof(uint2);  // 16 MiB

  if (ws_size >= KEY64_BYTES) {
    // NC=64, WPE=4: VGPR budget 128 -> regalloc has room, no spill risk
    uint2* keys = (uint2*)d_ws;
    bvh_screen4<64, 4><<<dim3(gx, 64), BLOCK, 0, stream>>>(tris, pts, keys);
    bvh_finish2<64><<<grid2, BLOCK, 0, stream>>>(tris, pts, keys, out);
  } else {
    // 8 MiB tier: NC=32, WPE=4
    uint2* keys = (uint2*)d_ws;
    bvh_screen4<32, 4><<<dim3(gx, 32), BLOCK, 0, stream>>>(tris, pts, keys);
    bvh_finish2<32><<<grid2, BLOCK, 0, stream>>>(tris, pts, keys, out);
  }
}

// Round 16
// 162.372 us; speedup vs baseline: 1.0398x; 1.0277x over previous
//
#include <hip/hip_runtime.h>
#include <math.h>

namespace {

typedef float v2f __attribute__((ext_vector_type(2)));

constexpr int B = 2;
constexpr int F = 4096;      // triangles per batch
constexpr int Q = 16384;     // points per batch
constexpr int NP = B * Q;    // 32768 total points
constexpr int BLOCK = 256;
constexpr int P4 = 4;        // points per lane in screen

// output layout in d_out (float32): dist [NP], closest [NP,3], faces [NP]
constexpr int OFF_DIST = 0;
constexpr int OFF_CP = NP;
constexpr int OFF_FACE = 4 * NP;

// ---------------- packed fp32 via inline asm (gfx90a+/CDNA4 VOP3P) ---------

__device__ __forceinline__ v2f pk_fma(v2f a, v2f b, v2f c) {   // a*b + c
  v2f d;
  asm("v_pk_fma_f32 %0, %1, %2, %3" : "=v"(d) : "v"(a), "v"(b), "v"(c));
  return d;
}
__device__ __forceinline__ v2f pk_fms(v2f a, v2f b, v2f c) {   // a*b - c
  v2f d;
  asm("v_pk_fma_f32 %0, %1, %2, %3 neg_lo:[0,0,1] neg_hi:[0,0,1]"
      : "=v"(d) : "v"(a), "v"(b), "v"(c));
  return d;
}
__device__ __forceinline__ v2f pk_nfma(v2f a, v2f b, v2f c) {  // c - a*b
  v2f d;
  asm("v_pk_fma_f32 %0, %1, %2, %3 neg_lo:[1,0,0] neg_hi:[1,0,0]"
      : "=v"(d) : "v"(a), "v"(b), "v"(c));
  return d;
}
__device__ __forceinline__ v2f pk_mul(v2f a, v2f b) {          // a*b
  v2f d;
  asm("v_pk_mul_f32 %0, %1, %2" : "=v"(d) : "v"(a), "v"(b));
  return d;
}
__device__ __forceinline__ v2f pk_add(v2f a, v2f b) {          // a+b
  v2f d;
  asm("v_pk_add_f32 %0, %1, %2" : "=v"(d) : "v"(a), "v"(b));
  return d;
}
__device__ __forceinline__ v2f pk_sub(v2f a, v2f b) {          // a-b
  v2f d;
  asm("v_pk_add_f32 %0, %1, %2 neg_lo:[0,1] neg_hi:[0,1]"
      : "=v"(d) : "v"(a), "v"(b));
  return d;
}

// ---------------- exact path (reference-bit-order, contract OFF) -----------

__device__ __forceinline__ float safediv(float num, float den) {
  #pragma clang fp contract(off)
  float d = (fabsf(den) > 1e-12f) ? den : 1.0f;
  return num / d;
}

__device__ __forceinline__ float clamp01(float x) {
  return fminf(fmaxf(x, 0.0f), 1.0f);
}

// Ericson region-based closest point on triangle, mirroring the JAX reference
// op-for-op (including the where/override order). Contract OFF inside.
__device__ __forceinline__ void closest_pt(
    float px, float py, float pz,
    float ax, float ay, float az,
    float bx, float by, float bz,
    float cx, float cy, float cz,
    float& rx, float& ry, float& rz) {
  #pragma clang fp contract(off)
  float abx = bx - ax, aby = by - ay, abz = bz - az;
  float acx = cx - ax, acy = cy - ay, acz = cz - az;
  float apx = px - ax, apy = py - ay, apz = pz - az;
  float d1 = (abx * apx + aby * apy) + abz * apz;
  float d2 = (acx * apx + acy * apy) + acz * apz;
  float bpx = px - bx, bpy = py - by, bpz = pz - bz;
  float d3 = (abx * bpx + aby * bpy) + abz * bpz;
  float d4 = (acx * bpx + acy * bpy) + acz * bpz;
  float cpx = px - cx, cpy = py - cy, cpz = pz - cz;
  float d5 = (abx * cpx + aby * cpy) + abz * cpz;
  float d6 = (acx * cpx + acy * cpy) + acz * cpz;

  float vc = d1 * d4 - d3 * d2;
  float vb = d5 * d2 - d1 * d6;
  float va = d3 * d6 - d5 * d4;

  float v_ab = clamp01(safediv(d1, d1 - d3));
  float w_ac = clamp01(safediv(d2, d2 - d6));
  float w_bc = clamp01(safediv(d4 - d3, (d4 - d3) + (d5 - d6)));

  float denom = (va + vb) + vc;
  float v = safediv(vb, denom);
  float w = safediv(vc, denom);

  float ox = ax + abx * v + acx * w;
  float oy = ay + aby * v + acy * w;
  float oz = az + abz * v + acz * w;

  bool m_bc = (va <= 0.0f) && (d4 - d3 >= 0.0f) && (d5 - d6 >= 0.0f);
  bool m_ac = (vb <= 0.0f) && (d2 >= 0.0f) && (d6 <= 0.0f);
  bool m_ab = (vc <= 0.0f) && (d1 >= 0.0f) && (d3 <= 0.0f);
  bool m_c  = (d6 >= 0.0f) && (d5 <= d6);
  bool m_b  = (d3 >= 0.0f) && (d4 <= d3);
  bool m_a  = (d1 <= 0.0f) && (d2 <= 0.0f);

  if (m_bc) { ox = bx + w_bc * (cx - bx); oy = by + w_bc * (cy - by); oz = bz + w_bc * (cz - bz); }
  if (m_ac) { ox = ax + w_ac * acx;       oy = ay + w_ac * acy;       oz = az + w_ac * acz; }
  if (m_ab) { ox = ax + v_ab * abx;       oy = ay + v_ab * aby;       oz = az + v_ab * abz; }
  if (m_c)  { ox = cx; oy = cy; oz = cz; }
  if (m_b)  { ox = bx; oy = by; oz = bz; }
  if (m_a)  { ox = ax; oy = ay; oz = az; }

  rx = ox; ry = oy; rz = oz;
}

__device__ __forceinline__ float exact_d2(
    float px, float py, float pz, const float* __restrict__ g /*a,b,c*/) {
  #pragma clang fp contract(off)
  float rx, ry, rz;
  closest_pt(px, py, pz,
             g[0], g[1], g[2], g[3], g[4], g[5], g[6], g[7], g[8],
             rx, ry, rz);
  float dx = px - rx, dy = py - ry, dz = pz - rz;
  return (dx * dx + dy * dy) + dz * dz;
}

// ---------------- key helpers ----------------------------------------------

__device__ __forceinline__ unsigned umin2(unsigned a, unsigned b) { return a < b ? a : b; }
__device__ __forceinline__ unsigned umax2(unsigned a, unsigned b) { return a > b ? a : b; }

// sorted top-2 insert via min/max (3 VOP2 ops)
__device__ __forceinline__ void ins2(unsigned k, unsigned& K1, unsigned& K2) {
  unsigned t = umax2(K1, k);
  K1 = umin2(K1, k);
  K2 = umin2(K2, t);
}

// sorted top-8 insert via min/max network
__device__ __forceinline__ void ins8(unsigned k,
    unsigned& K1, unsigned& K2, unsigned& K3, unsigned& K4,
    unsigned& K5, unsigned& K6, unsigned& K7, unsigned& K8) {
  unsigned t;
  t = umax2(K1, k); K1 = umin2(K1, k);
  k = t; t = umax2(K2, k); K2 = umin2(K2, k);
  k = t; t = umax2(K3, k); K3 = umin2(K3, k);
  k = t; t = umax2(K4, k); K4 = umin2(K4, k);
  k = t; t = umax2(K5, k); K5 = umin2(K5, k);
  k = t; t = umax2(K6, k); K6 = umin2(K6, k);
  k = t; t = umax2(K7, k); K7 = umin2(K7, k);
  K8 = umin2(K8, t);
}

// scalar finish of one point's screen value: returns packed key
__device__ __forceinline__ unsigned fin_one(
    float dint, float tabm, float tacm, float tbcm,
    float td1, float td2, float ap2m, float bp2, float t43d,
    float va, float vb, float vc,
    float aa, float bb, float cc, float pp, int gidx) {
  float tab = __builtin_amdgcn_fmed3f(tabm, 0.0f, 1.0f);
  float sab = fmaf(-tab, fmaf(-tab, aa, td1), ap2m);
  float tac = __builtin_amdgcn_fmed3f(tacm, 0.0f, 1.0f);
  float sac = fmaf(-tac, fmaf(-tac, bb, td2), ap2m);
  float tbc = __builtin_amdgcn_fmed3f(tbcm, 0.0f, 1.0f);
  float sbc = fmaf(-tbc, fmaf(-tbc, cc, t43d), bp2);
  float dseg = fminf(fminf(sab, sac), sbc);        // v_min3
  float mv   = fminf(fminf(va, vb), vc);           // v_min3
  float d = (mv > 0.0f) ? dint : dseg;
  d = fmaxf(d + pp, 0.0f);                         // restore |p|^2, keep >=0
  return (__float_as_uint(d) & 0xFFFFF000u) | (unsigned)gidx;
}

// screen outputs for one 2-point pair
struct SOut {
  v2f dint, tabm, tacm, tbcm, td1, td2, ap2m, bp2, t43d, va, vb, vc;
};

// all-packed screen math for 2 points vs 1 triangle (36 v_pk_* instrs)
__device__ __forceinline__ SOut screen_pair(
    v2f px, v2f py, v2f pz,
    v2f ABX, v2f ABY, v2f ABZ, v2f C1c,
    v2f ACX, v2f ACY, v2f ACZ, v2f C2c,
    v2f M2AX, v2f M2AY, v2f M2AZ, v2f CAA2,
    v2f AA, v2f BB, v2f ABAC,
    v2f RAA, v2f RBB, v2f RCC, v2f RDN) {
  SOut o;
  v2f d1 = pk_fma(px, ABX, pk_fma(py, ABY, pk_fma(pz, ABZ, C1c)));
  v2f d2 = pk_fma(px, ACX, pk_fma(py, ACY, pk_fma(pz, ACZ, C2c)));
  v2f ap2m = pk_fma(px, M2AX, pk_fma(py, M2AY, pk_fma(pz, M2AZ, CAA2)));
  v2f d3 = pk_sub(d1, AA), d6 = pk_sub(d2, BB);
  v2f d4 = pk_sub(d2, ABAC), d5 = pk_sub(d1, ABAC);
  v2f t43 = pk_sub(d4, d3);
  o.va = pk_nfma(d5, d4, pk_mul(d3, d6));   // d3*d6 - d5*d4
  o.vb = pk_nfma(d1, d6, pk_mul(d5, d2));   // d5*d2 - d1*d6
  o.vc = pk_nfma(d3, d2, pk_mul(d1, d4));   // d1*d4 - d3*d2
  o.td1 = pk_add(d1, d1);
  o.td2 = pk_add(d2, d2);
  v2f v = pk_mul(o.vb, RDN), w = pk_mul(o.vc, RDN);
  v2f h1 = pk_fma(v, AA, pk_fms(w, ABAC, o.td1));
  v2f h2 = pk_fma(w, BB, pk_fms(v, ABAC, o.td2));
  o.dint = pk_fma(v, h1, pk_fma(w, h2, ap2m));
  o.tabm = pk_mul(d1, RAA);
  o.tacm = pk_mul(d2, RBB);
  o.tbcm = pk_mul(t43, RCC);
  o.bp2 = pk_add(pk_sub(ap2m, o.td1), AA);
  o.t43d = pk_add(t43, t43);
  o.ap2m = ap2m;
  return o;
}

// ---------------- screen kernel: LDS splatted v2f records, P=4 -------------
// Per triangle: 40 floats = 20 x {c,c} granules (v2f loads -> aligned pairs):
//  [abx][aby][abz][c1][acx][acy][acz][c2][-2ax][-2ay][-2az][|a|2]
//  [aa][bb][abac][cc][raa][rbb][rcc][rdn]   (each stored twice)
// c1=-(a.ab), c2=-(a.ac). Screen works on d^2-|p|^2; |p|^2 restored in fin.

template <int NC, int WPE>
__global__ __launch_bounds__(BLOCK, WPE) void bvh_screen4(
    const float* __restrict__ tris,   // [B, F, 3, 3]
    const float* __restrict__ pts,    // [B, Q, 3]
    uint2* __restrict__ keys) {       // [NC, NP]
  constexpr int CFL = F / NC;
  __shared__ float4 s_rec[10 * CFL];  // AoS: 10 quads = 20 v2f granules / tri

  constexpr int BPB = (Q / P4) / BLOCK;          // 16
  const int batch = blockIdx.x / BPB;            // uniform per block
  const int j = (blockIdx.x % BPB) * BLOCK + threadIdx.x;  // 0 .. Q/4-1
  const int chunk = blockIdx.y;
  const int tri0 = chunk * CFL;
  const float* tb = tris + (size_t)batch * F * 9;

  for (int t = threadIdx.x; t < CFL; t += BLOCK) {
    const float* g = tb + (size_t)(tri0 + t) * 9;
    float ax = g[0], ay = g[1], az = g[2];
    float abx = g[3] - ax, aby = g[4] - ay, abz = g[5] - az;
    float acx = g[6] - ax, acy = g[7] - ay, acz = g[8] - az;
    float aa   = abx * abx + aby * aby + abz * abz;
    float bb   = acx * acx + acy * acy + acz * acz;
    float abac = abx * acx + aby * acy + abz * acz;
    float bcx = acx - abx, bcy = acy - aby, bcz = acz - abz;
    float cc   = bcx * bcx + bcy * bcy + bcz * bcz;
    float nx = aby * acz - abz * acy;
    float ny = abz * acx - abx * acz;
    float nz = abx * acy - aby * acx;
    float n2 = nx * nx + ny * ny + nz * nz;
    float raa = (aa > 1e-12f) ? 1.0f / aa : 1.0f;     // safediv-style guards
    float rbb = (bb > 1e-12f) ? 1.0f / bb : 1.0f;
    float rcc = (cc > 1e-12f) ? 1.0f / cc : 1.0f;
    float rdn = (n2 > 1e-12f) ? 1.0f / n2 : 1.0f;
    float c1 = -(ax * abx + ay * aby + az * abz);
    float c2 = -(ax * acx + ay * acy + az * acz);
    float caa2 = ax * ax + ay * ay + az * az;
    float4* s = &s_rec[t * 10];
    s[0] = make_float4(abx, abx, aby, aby);
    s[1] = make_float4(abz, abz, c1, c1);
    s[2] = make_float4(acx, acx, acy, acy);
    s[3] = make_float4(acz, acz, c2, c2);
    s[4] = make_float4(-2.0f * ax, -2.0f * ax, -2.0f * ay, -2.0f * ay);
    s[5] = make_float4(-2.0f * az, -2.0f * az, caa2, caa2);
    s[6] = make_float4(aa, aa, bb, bb);
    s[7] = make_float4(abac, abac, cc, cc);
    s[8] = make_float4(raa, raa, rbb, rbb);
    s[9] = make_float4(rcc, rcc, rdn, rdn);
  }
  __syncthreads();

  const int p0 = batch * Q + j;
  float px0 = pts[(p0          ) * 3 + 0], py0 = pts[(p0          ) * 3 + 1], pz0 = pts[(p0          ) * 3 + 2];
  float px1 = pts[(p0 + Q/4    ) * 3 + 0], py1 = pts[(p0 + Q/4    ) * 3 + 1], pz1 = pts[(p0 + Q/4    ) * 3 + 2];
  float px2 = pts[(p0 + Q/2    ) * 3 + 0], py2 = pts[(p0 + Q/2    ) * 3 + 1], pz2 = pts[(p0 + Q/2    ) * 3 + 2];
  float px3 = pts[(p0 + 3*(Q/4)) * 3 + 0], py3 = pts[(p0 + 3*(Q/4)) * 3 + 1], pz3 = pts[(p0 + 3*(Q/4)) * 3 + 2];

  const v2f pxA = {px0, px1}, pyA = {py0, py1}, pzA = {pz0, pz1};
  const v2f pxB = {px2, px3}, pyB = {py2, py3}, pzB = {pz2, pz3};
  const float pp0 = px0*px0 + py0*py0 + pz0*pz0;
  const float pp1 = px1*px1 + py1*py1 + pz1*pz1;
  const float pp2 = px2*px2 + py2*py2 + pz2*pz2;
  const float pp3 = px3*px3 + py3*py3 + pz3*pz3;

  unsigned A1 = ~0u, A2 = ~0u, Bk1 = ~0u, Bk2 = ~0u;
  unsigned C1 = ~0u, C2 = ~0u, D1 = ~0u, D2 = ~0u;

  for (int t = 0; t < CFL; ++t) {
    const float* sp = (const float*)&s_rec[t * 10];  // uniform addr
    v2f ABX  = *(const v2f*)(sp + 0);
    v2f ABY  = *(const v2f*)(sp + 2);
    v2f ABZ  = *(const v2f*)(sp + 4);
    v2f C1c  = *(const v2f*)(sp + 6);
    v2f ACX  = *(const v2f*)(sp + 8);
    v2f ACY  = *(const v2f*)(sp + 10);
    v2f ACZ  = *(const v2f*)(sp + 12);
    v2f C2c  = *(const v2f*)(sp + 14);
    v2f M2AX = *(const v2f*)(sp + 16);
    v2f M2AY = *(const v2f*)(sp + 18);
    v2f M2AZ = *(const v2f*)(sp + 20);
    v2f CAA2 = *(const v2f*)(sp + 22);
    v2f AA   = *(const v2f*)(sp + 24);
    v2f BBv  = *(const v2f*)(sp + 26);
    v2f ABAC = *(const v2f*)(sp + 28);
    v2f CCv  = *(const v2f*)(sp + 30);
    v2f RAA  = *(const v2f*)(sp + 32);
    v2f RBB  = *(const v2f*)(sp + 34);
    v2f RCC  = *(const v2f*)(sp + 36);
    v2f RDN  = *(const v2f*)(sp + 38);
    const int gidx = tri0 + t;
    const float aa_s = AA.x, bb_s = BBv.x, cc_s = CCv.x;

    // ---- pair A (points 0,1): forced v_pk_*_f32 ----
    {
      SOut o = screen_pair(pxA, pyA, pzA, ABX, ABY, ABZ, C1c,
                           ACX, ACY, ACZ, C2c, M2AX, M2AY, M2AZ, CAA2,
                           AA, BBv, ABAC, RAA, RBB, RCC, RDN);
      ins2(fin_one(o.dint.x, o.tabm.x, o.tacm.x, o.tbcm.x, o.td1.x, o.td2.x,
                   o.ap2m.x, o.bp2.x, o.t43d.x, o.va.x, o.vb.x, o.vc.x,
                   aa_s, bb_s, cc_s, pp0, gidx), A1, A2);
      ins2(fin_one(o.dint.y, o.tabm.y, o.tacm.y, o.tbcm.y, o.td1.y, o.td2.y,
                   o.ap2m.y, o.bp2.y, o.t43d.y, o.va.y, o.vb.y, o.vc.y,
                   aa_s, bb_s, cc_s, pp1, gidx), Bk1, Bk2);
    }
    // ---- pair B (points 2,3) ----
    {
      SOut o = screen_pair(pxB, pyB, pzB, ABX, ABY, ABZ, C1c,
                           ACX, ACY, ACZ, C2c, M2AX, M2AY, M2AZ, CAA2,
                           AA, BBv, ABAC, RAA, RBB, RCC, RDN);
      ins2(fin_one(o.dint.x, o.tabm.x, o.tacm.x, o.tbcm.x, o.td1.x, o.td2.x,
                   o.ap2m.x, o.bp2.x, o.t43d.x, o.va.x, o.vb.x, o.vc.x,
                   aa_s, bb_s, cc_s, pp2, gidx), C1, C2);
      ins2(fin_one(o.dint.y, o.tabm.y, o.tacm.y, o.tbcm.y, o.td1.y, o.td2.y,
                   o.ap2m.y, o.bp2.y, o.t43d.y, o.va.y, o.vb.y, o.vc.y,
                   aa_s, bb_s, cc_s, pp3, gidx), D1, D2);
    }
  }

  keys[(size_t)chunk * NP + p0            ] = make_uint2(A1, A2);
  keys[(size_t)chunk * NP + p0 + Q/4      ] = make_uint2(Bk1, Bk2);
  keys[(size_t)chunk * NP + p0 + Q/2      ] = make_uint2(C1, C2);
  keys[(size_t)chunk * NP + p0 + 3*(Q/4)  ] = make_uint2(D1, D2);
}

// ---------------- finish: merge 2*NC keys -> top-8 -> exact ----------------

template <int NC>
__global__ __launch_bounds__(BLOCK) void bvh_finish2(
    const float* __restrict__ tris,
    const float* __restrict__ pts,
    const uint2* __restrict__ keys,
    float* __restrict__ out) {
  const int gpt = blockIdx.x * BLOCK + threadIdx.x;
  if (gpt >= NP) return;

  unsigned K1 = ~0u, K2 = ~0u, K3 = ~0u, K4 = ~0u;
  unsigned K5 = ~0u, K6 = ~0u, K7 = ~0u, K8 = ~0u;
  for (int c = 0; c < NC; ++c) {
    uint2 k = keys[(size_t)c * NP + gpt];
    ins8(k.x, K1, K2, K3, K4, K5, K6, K7, K8);
    ins8(k.y, K1, K2, K3, K4, K5, K6, K7, K8);
  }

  const int batch = gpt / Q;
  const float* tb = tris + (size_t)batch * F * 9;
  const float px = pts[gpt * 3 + 0];
  const float py = pts[gpt * 3 + 1];
  const float pz = pts[gpt * 3 + 2];

  // order-independent first-occurrence argmin over the 8 candidates
  float be = INFINITY;
  int bi = 0x7FFFFFFF;
  #define CAND(Kx) { int t_ = (int)(Kx & 0xFFFu); \
    float d_ = exact_d2(px, py, pz, tb + (size_t)t_ * 9); \
    if (d_ < be || (d_ == be && t_ < bi)) { be = d_; bi = t_; } }
  CAND(K1) CAND(K2) CAND(K3) CAND(K4) CAND(K5) CAND(K6) CAND(K7) CAND(K8)
  #undef CAND

  const float* tr = tb + (size_t)bi * 9;
  float rx, ry, rz;
  closest_pt(px, py, pz,
             tr[0], tr[1], tr[2], tr[3], tr[4], tr[5], tr[6], tr[7], tr[8],
             rx, ry, rz);

  out[OFF_DIST + gpt] = be;
  out[OFF_CP + gpt * 3 + 0] = rx;
  out[OFF_CP + gpt * 3 + 1] = ry;
  out[OFF_CP + gpt * 3 + 2] = rz;
  out[OFF_FACE + gpt] = (float)bi;
}

}  // namespace

extern "C" void kernel_launch(void* const* d_in, const int* in_sizes, int n_in,
                              void* d_out, int out_size, void* d_ws, size_t ws_size,
                              hipStream_t stream) {
  const float* tris = (const float*)d_in[0];
  const float* pts  = (const float*)d_in[1];
  float* out = (float*)d_out;

  dim3 grid2((NP + BLOCK - 1) / BLOCK);
  const int gx = B * ((Q / P4) / BLOCK);   // 32 blocks in x

  constexpr size_t KEY64_BYTES = (size_t)64 * NP * sizeof(uint2);  // 16 MiB

  if (ws_size >= KEY64_BYTES) {
    uint2* keys = (uint2*)d_ws;
    bvh_screen4<64, 4><<<dim3(gx, 64), BLOCK, 0, stream>>>(tris, pts, keys);
    bvh_finish2<64><<<grid2, BLOCK, 0, stream>>>(tris, pts, keys, out);
  } else {
    uint2* keys = (uint2*)d_ws;
    bvh_screen4<32, 4><<<dim3(gx, 32), BLOCK, 0, stream>>>(tris, pts, keys);
    bvh_finish2<32><<<grid2, BLOCK, 0, stream>>>(tris, pts, keys, out);
  }
}

// Round 17
// 162.040 us; speedup vs baseline: 1.0420x; 1.0020x over previous
//
#include <hip/hip_runtime.h>
#include <math.h>

namespace {

typedef float v2f __attribute__((ext_vector_type(2)));

constexpr int B = 2;
constexpr int F = 4096;      // triangles per batch
constexpr int Q = 16384;     // points per batch
constexpr int NP = B * Q;    // 32768 total points
constexpr int BLOCK = 256;
constexpr int P4 = 4;        // points per lane in screen

// output layout in d_out (float32): dist [NP], closest [NP,3], faces [NP]
constexpr int OFF_DIST = 0;
constexpr int OFF_CP = NP;
constexpr int OFF_FACE = 4 * NP;

// ---------------- packed fp32 via inline asm (gfx90a+/CDNA4 VOP3P) ---------

__device__ __forceinline__ v2f pk_fma(v2f a, v2f b, v2f c) {   // a*b + c
  v2f d;
  asm("v_pk_fma_f32 %0, %1, %2, %3" : "=v"(d) : "v"(a), "v"(b), "v"(c));
  return d;
}
__device__ __forceinline__ v2f pk_fms(v2f a, v2f b, v2f c) {   // a*b - c
  v2f d;
  asm("v_pk_fma_f32 %0, %1, %2, %3 neg_lo:[0,0,1] neg_hi:[0,0,1]"
      : "=v"(d) : "v"(a), "v"(b), "v"(c));
  return d;
}
__device__ __forceinline__ v2f pk_nfma(v2f a, v2f b, v2f c) {  // c - a*b
  v2f d;
  asm("v_pk_fma_f32 %0, %1, %2, %3 neg_lo:[1,0,0] neg_hi:[1,0,0]"
      : "=v"(d) : "v"(a), "v"(b), "v"(c));
  return d;
}
__device__ __forceinline__ v2f pk_mul(v2f a, v2f b) {          // a*b
  v2f d;
  asm("v_pk_mul_f32 %0, %1, %2" : "=v"(d) : "v"(a), "v"(b));
  return d;
}
__device__ __forceinline__ v2f pk_add(v2f a, v2f b) {          // a+b
  v2f d;
  asm("v_pk_add_f32 %0, %1, %2" : "=v"(d) : "v"(a), "v"(b));
  return d;
}
__device__ __forceinline__ v2f pk_sub(v2f a, v2f b) {          // a-b
  v2f d;
  asm("v_pk_add_f32 %0, %1, %2 neg_lo:[0,1] neg_hi:[0,1]"
      : "=v"(d) : "v"(a), "v"(b));
  return d;
}

// ---------------- exact path (reference-bit-order, contract OFF) -----------

__device__ __forceinline__ float safediv(float num, float den) {
  #pragma clang fp contract(off)
  float d = (fabsf(den) > 1e-12f) ? den : 1.0f;
  return num / d;
}

__device__ __forceinline__ float clamp01(float x) {
  return fminf(fmaxf(x, 0.0f), 1.0f);
}

// Ericson region-based closest point on triangle, mirroring the JAX reference
// op-for-op (including the where/override order). Contract OFF inside.
__device__ __forceinline__ void closest_pt(
    float px, float py, float pz,
    float ax, float ay, float az,
    float bx, float by, float bz,
    float cx, float cy, float cz,
    float& rx, float& ry, float& rz) {
  #pragma clang fp contract(off)
  float abx = bx - ax, aby = by - ay, abz = bz - az;
  float acx = cx - ax, acy = cy - ay, acz = cz - az;
  float apx = px - ax, apy = py - ay, apz = pz - az;
  float d1 = (abx * apx + aby * apy) + abz * apz;
  float d2 = (acx * apx + acy * apy) + acz * apz;
  float bpx = px - bx, bpy = py - by, bpz = pz - bz;
  float d3 = (abx * bpx + aby * bpy) + abz * bpz;
  float d4 = (acx * bpx + acy * bpy) + acz * bpz;
  float cpx = px - cx, cpy = py - cy, cpz = pz - cz;
  float d5 = (abx * cpx + aby * cpy) + abz * cpz;
  float d6 = (acx * cpx + acy * cpy) + acz * cpz;

  float vc = d1 * d4 - d3 * d2;
  float vb = d5 * d2 - d1 * d6;
  float va = d3 * d6 - d5 * d4;

  float v_ab = clamp01(safediv(d1, d1 - d3));
  float w_ac = clamp01(safediv(d2, d2 - d6));
  float w_bc = clamp01(safediv(d4 - d3, (d4 - d3) + (d5 - d6)));

  float denom = (va + vb) + vc;
  float v = safediv(vb, denom);
  float w = safediv(vc, denom);

  float ox = ax + abx * v + acx * w;
  float oy = ay + aby * v + acy * w;
  float oz = az + abz * v + acz * w;

  bool m_bc = (va <= 0.0f) && (d4 - d3 >= 0.0f) && (d5 - d6 >= 0.0f);
  bool m_ac = (vb <= 0.0f) && (d2 >= 0.0f) && (d6 <= 0.0f);
  bool m_ab = (vc <= 0.0f) && (d1 >= 0.0f) && (d3 <= 0.0f);
  bool m_c  = (d6 >= 0.0f) && (d5 <= d6);
  bool m_b  = (d3 >= 0.0f) && (d4 <= d3);
  bool m_a  = (d1 <= 0.0f) && (d2 <= 0.0f);

  if (m_bc) { ox = bx + w_bc * (cx - bx); oy = by + w_bc * (cy - by); oz = bz + w_bc * (cz - bz); }
  if (m_ac) { ox = ax + w_ac * acx;       oy = ay + w_ac * acy;       oz = az + w_ac * acz; }
  if (m_ab) { ox = ax + v_ab * abx;       oy = ay + v_ab * aby;       oz = az + v_ab * abz; }
  if (m_c)  { ox = cx; oy = cy; oz = cz; }
  if (m_b)  { ox = bx; oy = by; oz = bz; }
  if (m_a)  { ox = ax; oy = ay; oz = az; }

  rx = ox; ry = oy; rz = oz;
}

__device__ __forceinline__ float exact_d2(
    float px, float py, float pz, const float* __restrict__ g /*a,b,c*/) {
  #pragma clang fp contract(off)
  float rx, ry, rz;
  closest_pt(px, py, pz,
             g[0], g[1], g[2], g[3], g[4], g[5], g[6], g[7], g[8],
             rx, ry, rz);
  float dx = px - rx, dy = py - ry, dz = pz - rz;
  return (dx * dx + dy * dy) + dz * dz;
}

// ---------------- key helpers ----------------------------------------------

__device__ __forceinline__ unsigned umin2(unsigned a, unsigned b) { return a < b ? a : b; }
__device__ __forceinline__ unsigned umax2(unsigned a, unsigned b) { return a > b ? a : b; }

// sorted top-2 insert via min/max (3 VOP2 ops)
__device__ __forceinline__ void ins2(unsigned k, unsigned& K1, unsigned& K2) {
  unsigned t = umax2(K1, k);
  K1 = umin2(K1, k);
  K2 = umin2(K2, t);
}

// sorted top-8 insert via min/max network
__device__ __forceinline__ void ins8(unsigned k,
    unsigned& K1, unsigned& K2, unsigned& K3, unsigned& K4,
    unsigned& K5, unsigned& K6, unsigned& K7, unsigned& K8) {
  unsigned t;
  t = umax2(K1, k); K1 = umin2(K1, k);
  k = t; t = umax2(K2, k); K2 = umin2(K2, k);
  k = t; t = umax2(K3, k); K3 = umin2(K3, k);
  k = t; t = umax2(K4, k); K4 = umin2(K4, k);
  k = t; t = umax2(K5, k); K5 = umin2(K5, k);
  k = t; t = umax2(K6, k); K6 = umin2(K6, k);
  k = t; t = umax2(K7, k); K7 = umin2(K7, k);
  K8 = umin2(K8, t);
}

// scalar finish of one point's screen value: returns packed key
__device__ __forceinline__ unsigned fin_one(
    float dint, float tabm, float tacm, float tbcm,
    float td1, float td2, float ap2m, float bp2, float t43d,
    float va, float vb, float vc,
    float aa, float bb, float cc, float pp, int gidx) {
  float tab = __builtin_amdgcn_fmed3f(tabm, 0.0f, 1.0f);
  float sab = fmaf(-tab, fmaf(-tab, aa, td1), ap2m);
  float tac = __builtin_amdgcn_fmed3f(tacm, 0.0f, 1.0f);
  float sac = fmaf(-tac, fmaf(-tac, bb, td2), ap2m);
  float tbc = __builtin_amdgcn_fmed3f(tbcm, 0.0f, 1.0f);
  float sbc = fmaf(-tbc, fmaf(-tbc, cc, t43d), bp2);
  float dseg = fminf(fminf(sab, sac), sbc);        // v_min3
  float mv   = fminf(fminf(va, vb), vc);           // v_min3
  float d = (mv > 0.0f) ? dint : dseg;
  d = fmaxf(d + pp, 0.0f);                         // restore |p|^2, keep >=0
  return (__float_as_uint(d) & 0xFFFFF000u) | (unsigned)gidx;
}

// screen outputs for one 2-point pair
struct SOut {
  v2f dint, tabm, tacm, tbcm, td1, td2, ap2m, bp2, t43d, va, vb, vc;
};

// all-packed screen math for 2 points vs 1 triangle (36 v_pk_* instrs)
__device__ __forceinline__ SOut screen_pair(
    v2f px, v2f py, v2f pz,
    v2f ABX, v2f ABY, v2f ABZ, v2f C1c,
    v2f ACX, v2f ACY, v2f ACZ, v2f C2c,
    v2f M2AX, v2f M2AY, v2f M2AZ, v2f CAA2,
    v2f AA, v2f BB, v2f ABAC,
    v2f RAA, v2f RBB, v2f RCC, v2f RDN) {
  SOut o;
  v2f d1 = pk_fma(px, ABX, pk_fma(py, ABY, pk_fma(pz, ABZ, C1c)));
  v2f d2 = pk_fma(px, ACX, pk_fma(py, ACY, pk_fma(pz, ACZ, C2c)));
  v2f ap2m = pk_fma(px, M2AX, pk_fma(py, M2AY, pk_fma(pz, M2AZ, CAA2)));
  v2f d3 = pk_sub(d1, AA), d6 = pk_sub(d2, BB);
  v2f d4 = pk_sub(d2, ABAC), d5 = pk_sub(d1, ABAC);
  v2f t43 = pk_sub(d4, d3);
  o.va = pk_nfma(d5, d4, pk_mul(d3, d6));   // d3*d6 - d5*d4
  o.vb = pk_nfma(d1, d6, pk_mul(d5, d2));   // d5*d2 - d1*d6
  o.vc = pk_nfma(d3, d2, pk_mul(d1, d4));   // d1*d4 - d3*d2
  o.td1 = pk_add(d1, d1);
  o.td2 = pk_add(d2, d2);
  v2f v = pk_mul(o.vb, RDN), w = pk_mul(o.vc, RDN);
  v2f h1 = pk_fma(v, AA, pk_fms(w, ABAC, o.td1));
  v2f h2 = pk_fma(w, BB, pk_fms(v, ABAC, o.td2));
  o.dint = pk_fma(v, h1, pk_fma(w, h2, ap2m));
  o.tabm = pk_mul(d1, RAA);
  o.tacm = pk_mul(d2, RBB);
  o.tbcm = pk_mul(t43, RCC);
  o.bp2 = pk_add(pk_sub(ap2m, o.td1), AA);
  o.t43d = pk_add(t43, t43);
  o.ap2m = ap2m;
  return o;
}

// ---------------- screen kernel: LDS splatted v2f records, P=4 -------------
// Per triangle: 40 floats = 20 x {c,c} granules (v2f loads -> aligned pairs).
// amdgpu_waves_per_eu(2,3): cap the allocator's occupancy target so the full
// record set + SOut stays in registers (no remat / alignment copy shuffling).

template <int NC>
__global__ __launch_bounds__(BLOCK)
__attribute__((amdgpu_waves_per_eu(2, 3)))
void bvh_screen4(
    const float* __restrict__ tris,   // [B, F, 3, 3]
    const float* __restrict__ pts,    // [B, Q, 3]
    uint2* __restrict__ keys) {       // [NC, NP]
  constexpr int CFL = F / NC;
  __shared__ float4 s_rec[10 * CFL];  // AoS: 10 quads = 20 v2f granules / tri

  constexpr int BPB = (Q / P4) / BLOCK;          // 16
  const int batch = blockIdx.x / BPB;            // uniform per block
  const int j = (blockIdx.x % BPB) * BLOCK + threadIdx.x;  // 0 .. Q/4-1
  const int chunk = blockIdx.y;
  const int tri0 = chunk * CFL;
  const float* tb = tris + (size_t)batch * F * 9;

  for (int t = threadIdx.x; t < CFL; t += BLOCK) {
    const float* g = tb + (size_t)(tri0 + t) * 9;
    float ax = g[0], ay = g[1], az = g[2];
    float abx = g[3] - ax, aby = g[4] - ay, abz = g[5] - az;
    float acx = g[6] - ax, acy = g[7] - ay, acz = g[8] - az;
    float aa   = abx * abx + aby * aby + abz * abz;
    float bb   = acx * acx + acy * acy + acz * acz;
    float abac = abx * acx + aby * acy + abz * acz;
    float bcx = acx - abx, bcy = acy - aby, bcz = acz - abz;
    float cc   = bcx * bcx + bcy * bcy + bcz * bcz;
    float nx = aby * acz - abz * acy;
    float ny = abz * acx - abx * acz;
    float nz = abx * acy - aby * acx;
    float n2 = nx * nx + ny * ny + nz * nz;
    float raa = (aa > 1e-12f) ? 1.0f / aa : 1.0f;     // safediv-style guards
    float rbb = (bb > 1e-12f) ? 1.0f / bb : 1.0f;
    float rcc = (cc > 1e-12f) ? 1.0f / cc : 1.0f;
    float rdn = (n2 > 1e-12f) ? 1.0f / n2 : 1.0f;
    float c1 = -(ax * abx + ay * aby + az * abz);
    float c2 = -(ax * acx + ay * acy + az * acz);
    float caa2 = ax * ax + ay * ay + az * az;
    float4* s = &s_rec[t * 10];
    s[0] = make_float4(abx, abx, aby, aby);
    s[1] = make_float4(abz, abz, c1, c1);
    s[2] = make_float4(acx, acx, acy, acy);
    s[3] = make_float4(acz, acz, c2, c2);
    s[4] = make_float4(-2.0f * ax, -2.0f * ax, -2.0f * ay, -2.0f * ay);
    s[5] = make_float4(-2.0f * az, -2.0f * az, caa2, caa2);
    s[6] = make_float4(aa, aa, bb, bb);
    s[7] = make_float4(abac, abac, cc, cc);
    s[8] = make_float4(raa, raa, rbb, rbb);
    s[9] = make_float4(rcc, rcc, rdn, rdn);
  }
  __syncthreads();

  const int p0 = batch * Q + j;
  float px0 = pts[(p0          ) * 3 + 0], py0 = pts[(p0          ) * 3 + 1], pz0 = pts[(p0          ) * 3 + 2];
  float px1 = pts[(p0 + Q/4    ) * 3 + 0], py1 = pts[(p0 + Q/4    ) * 3 + 1], pz1 = pts[(p0 + Q/4    ) * 3 + 2];
  float px2 = pts[(p0 + Q/2    ) * 3 + 0], py2 = pts[(p0 + Q/2    ) * 3 + 1], pz2 = pts[(p0 + Q/2    ) * 3 + 2];
  float px3 = pts[(p0 + 3*(Q/4)) * 3 + 0], py3 = pts[(p0 + 3*(Q/4)) * 3 + 1], pz3 = pts[(p0 + 3*(Q/4)) * 3 + 2];

  const v2f pxA = {px0, px1}, pyA = {py0, py1}, pzA = {pz0, pz1};
  const v2f pxB = {px2, px3}, pyB = {py2, py3}, pzB = {pz2, pz3};
  const float pp0 = px0*px0 + py0*py0 + pz0*pz0;
  const float pp1 = px1*px1 + py1*py1 + pz1*pz1;
  const float pp2 = px2*px2 + py2*py2 + pz2*pz2;
  const float pp3 = px3*px3 + py3*py3 + pz3*pz3;

  unsigned A1 = ~0u, A2 = ~0u, Bk1 = ~0u, Bk2 = ~0u;
  unsigned C1 = ~0u, C2 = ~0u, D1 = ~0u, D2 = ~0u;

  for (int t = 0; t < CFL; ++t) {
    const float* sp = (const float*)&s_rec[t * 10];  // uniform addr
    v2f ABX  = *(const v2f*)(sp + 0);
    v2f ABY  = *(const v2f*)(sp + 2);
    v2f ABZ  = *(const v2f*)(sp + 4);
    v2f C1c  = *(const v2f*)(sp + 6);
    v2f ACX  = *(const v2f*)(sp + 8);
    v2f ACY  = *(const v2f*)(sp + 10);
    v2f ACZ  = *(const v2f*)(sp + 12);
    v2f C2c  = *(const v2f*)(sp + 14);
    v2f M2AX = *(const v2f*)(sp + 16);
    v2f M2AY = *(const v2f*)(sp + 18);
    v2f M2AZ = *(const v2f*)(sp + 20);
    v2f CAA2 = *(const v2f*)(sp + 22);
    v2f AA   = *(const v2f*)(sp + 24);
    v2f BBv  = *(const v2f*)(sp + 26);
    v2f ABAC = *(const v2f*)(sp + 28);
    v2f CCv  = *(const v2f*)(sp + 30);
    v2f RAA  = *(const v2f*)(sp + 32);
    v2f RBB  = *(const v2f*)(sp + 34);
    v2f RCC  = *(const v2f*)(sp + 36);
    v2f RDN  = *(const v2f*)(sp + 38);
    const int gidx = tri0 + t;
    const float aa_s = AA.x, bb_s = BBv.x, cc_s = CCv.x;

    // ---- pair A (points 0,1): forced v_pk_*_f32 ----
    {
      SOut o = screen_pair(pxA, pyA, pzA, ABX, ABY, ABZ, C1c,
                           ACX, ACY, ACZ, C2c, M2AX, M2AY, M2AZ, CAA2,
                           AA, BBv, ABAC, RAA, RBB, RCC, RDN);
      ins2(fin_one(o.dint.x, o.tabm.x, o.tacm.x, o.tbcm.x, o.td1.x, o.td2.x,
                   o.ap2m.x, o.bp2.x, o.t43d.x, o.va.x, o.vb.x, o.vc.x,
                   aa_s, bb_s, cc_s, pp0, gidx), A1, A2);
      ins2(fin_one(o.dint.y, o.tabm.y, o.tacm.y, o.tbcm.y, o.td1.y, o.td2.y,
                   o.ap2m.y, o.bp2.y, o.t43d.y, o.va.y, o.vb.y, o.vc.y,
                   aa_s, bb_s, cc_s, pp1, gidx), Bk1, Bk2);
    }
    // ---- pair B (points 2,3) ----
    {
      SOut o = screen_pair(pxB, pyB, pzB, ABX, ABY, ABZ, C1c,
                           ACX, ACY, ACZ, C2c, M2AX, M2AY, M2AZ, CAA2,
                           AA, BBv, ABAC, RAA, RBB, RCC, RDN);
      ins2(fin_one(o.dint.x, o.tabm.x, o.tacm.x, o.tbcm.x, o.td1.x, o.td2.x,
                   o.ap2m.x, o.bp2.x, o.t43d.x, o.va.x, o.vb.x, o.vc.x,
                   aa_s, bb_s, cc_s, pp2, gidx), C1, C2);
      ins2(fin_one(o.dint.y, o.tabm.y, o.tacm.y, o.tbcm.y, o.td1.y, o.td2.y,
                   o.ap2m.y, o.bp2.y, o.t43d.y, o.va.y, o.vb.y, o.vc.y,
                   aa_s, bb_s, cc_s, pp3, gidx), D1, D2);
    }
  }

  keys[(size_t)chunk * NP + p0            ] = make_uint2(A1, A2);
  keys[(size_t)chunk * NP + p0 + Q/4      ] = make_uint2(Bk1, Bk2);
  keys[(size_t)chunk * NP + p0 + Q/2      ] = make_uint2(C1, C2);
  keys[(size_t)chunk * NP + p0 + 3*(Q/4)  ] = make_uint2(D1, D2);
}

// ---------------- finish: merge 2*NC keys -> top-8 -> exact ----------------

template <int NC>
__global__ __launch_bounds__(BLOCK) void bvh_finish2(
    const float* __restrict__ tris,
    const float* __restrict__ pts,
    const uint2* __restrict__ keys,
    float* __restrict__ out) {
  const int gpt = blockIdx.x * BLOCK + threadIdx.x;
  if (gpt >= NP) return;

  unsigned K1 = ~0u, K2 = ~0u, K3 = ~0u, K4 = ~0u;
  unsigned K5 = ~0u, K6 = ~0u, K7 = ~0u, K8 = ~0u;
  for (int c = 0; c < NC; ++c) {
    uint2 k = keys[(size_t)c * NP + gpt];
    ins8(k.x, K1, K2, K3, K4, K5, K6, K7, K8);
    ins8(k.y, K1, K2, K3, K4, K5, K6, K7, K8);
  }

  const int batch = gpt / Q;
  const float* tb = tris + (size_t)batch * F * 9;
  const float px = pts[gpt * 3 + 0];
  const float py = pts[gpt * 3 + 1];
  const float pz = pts[gpt * 3 + 2];

  // order-independent first-occurrence argmin over the 8 candidates
  float be = INFINITY;
  int bi = 0x7FFFFFFF;
  #define CAND(Kx) { int t_ = (int)(Kx & 0xFFFu); \
    float d_ = exact_d2(px, py, pz, tb + (size_t)t_ * 9); \
    if (d_ < be || (d_ == be && t_ < bi)) { be = d_; bi = t_; } }
  CAND(K1) CAND(K2) CAND(K3) CAND(K4) CAND(K5) CAND(K6) CAND(K7) CAND(K8)
  #undef CAND

  const float* tr = tb + (size_t)bi * 9;
  float rx, ry, rz;
  closest_pt(px, py, pz,
             tr[0], tr[1], tr[2], tr[3], tr[4], tr[5], tr[6], tr[7], tr[8],
             rx, ry, rz);

  out[OFF_DIST + gpt] = be;
  out[OFF_CP + gpt * 3 + 0] = rx;
  out[OFF_CP + gpt * 3 + 1] = ry;
  out[OFF_CP + gpt * 3 + 2] = rz;
  out[OFF_FACE + gpt] = (float)bi;
}

}  // namespace

extern "C" void kernel_launch(void* const* d_in, const int* in_sizes, int n_in,
                              void* d_out, int out_size, void* d_ws, size_t ws_size,
                              hipStream_t stream) {
  const float* tris = (const float*)d_in[0];
  const float* pts  = (const float*)d_in[1];
  float* out = (float*)d_out;

  dim3 grid2((NP + BLOCK - 1) / BLOCK);
  const int gx = B * ((Q / P4) / BLOCK);   // 32 blocks in x

  constexpr size_t KEY64_BYTES = (size_t)64 * NP * sizeof(uint2);  // 16 MiB

  if (ws_size >= KEY64_BYTES) {
    uint2* keys = (uint2*)d_ws;
    bvh_screen4<64><<<dim3(gx, 64), BLOCK, 0, stream>>>(tris, pts, keys);
    bvh_finish2<64><<<grid2, BLOCK, 0, stream>>>(tris, pts, keys, out);
  } else {
    uint2* keys = (uint2*)d_ws;
    bvh_screen4<32><<<dim3(gx, 32), BLOCK, 0, stream>>>(tris, pts, keys);
    bvh_finish2<32><<<grid2, BLOCK, 0, stream>>>(tris, pts, keys, out);
  }
}